// Round 1
// baseline (5492.733 us; speedup 1.0000x reference)
//
#include <hip/hip_runtime.h>

#define USER_NUM 100000
#define ITEM_NUM 50000
#define NN (USER_NUM + ITEM_NUM)
#define EMB 64
#define N_EDGES 8000000
#define EPS_C 0.1f
#define PROTO 4000

// ego = concat(user_emb, item_emb)
__global__ __launch_bounds__(256) void concat_kernel(const float* __restrict__ u,
                                                     const float* __restrict__ it,
                                                     float* __restrict__ out) {
    long i = (long)blockIdx.x * 256 + threadIdx.x;
    const long usz = (long)USER_NUM * EMB;
    const long tot = (long)NN * EMB;
    if (i >= tot) return;
    out[i] = (i < usz) ? u[i] : it[i - usz];
}

// y[rows[e]] += vals[e] * x[cols[e]]  — one 64-lane wave per edge, lane = emb idx
__global__ __launch_bounds__(256) void spmm_atomic_kernel(const int* __restrict__ rows,
                                                          const int* __restrict__ cols,
                                                          const float* __restrict__ vals,
                                                          const float* __restrict__ x,
                                                          float* __restrict__ y) {
    long t = (long)blockIdx.x * 256 + threadIdx.x;
    int e = (int)(t >> 6);
    int lane = (int)(t & 63);
    if (e >= N_EDGES) return;
    int c = cols[e];
    int r = rows[e];
    float v = vals[e];
    float xv = x[(long)c * EMB + lane];
    atomicAdd(&y[(long)r * EMB + lane], v * xv);
}

// ego += sign(ego) * l2_normalize(noise_k) * EPS  (in place); acc update
// mode 0: acc = ego'   mode 1: acc += ego'   mode 2: acc = (acc + ego') / 3
__global__ __launch_bounds__(256) void noise_acc_kernel(float* __restrict__ ego,
                                                        const float* __restrict__ noise_k,
                                                        float* __restrict__ acc,
                                                        int mode) {
    long t = (long)blockIdx.x * 256 + threadIdx.x;
    int node = (int)(t >> 6);
    int lane = (int)(t & 63);
    if (node >= NN) return;
    long idx = (long)node * EMB + lane;
    float nv = noise_k[idx];
    float s = nv * nv;
    // wave-wide (64-lane) reduction: row norm of noise
    #pragma unroll
    for (int off = 32; off >= 1; off >>= 1) s += __shfl_xor(s, off, 64);
    float nrm = fmaxf(sqrtf(s), 1e-12f);
    float e0 = ego[idx];
    float sgn = (e0 > 0.0f) ? 1.0f : ((e0 < 0.0f) ? -1.0f : 0.0f);
    float e1 = e0 + sgn * (nv / nrm) * EPS_C;
    ego[idx] = e1;
    if (mode == 0)      acc[idx] = e1;
    else if (mode == 1) acc[idx] += e1;
    else                acc[idx] = (acc[idx] + e1) * (1.0f / 3.0f);
}

extern "C" void kernel_launch(void* const* d_in, const int* in_sizes, int n_in,
                              void* d_out, int out_size, void* d_ws, size_t ws_size,
                              hipStream_t stream) {
    const float* user_emb   = (const float*)d_in[0];
    const float* item_emb   = (const float*)d_in[1];
    const float* user_proto = (const float*)d_in[2];
    const float* item_proto = (const float*)d_in[3];
    const int*   rows       = (const int*)d_in[4];
    const int*   cols       = (const int*)d_in[5];
    const float* vals       = (const float*)d_in[6];
    const float* noise      = (const float*)d_in[7];
    float* out = (float*)d_out;

    const size_t SZ = (size_t)NN * EMB * sizeof(float);
    float* egoA = (float*)d_ws;
    float* egoB = (float*)((char*)d_ws + SZ);
    float* acc  = out;  // first NN*EMB floats of d_out == all_embeddings

    const int elemTotal = NN * EMB;              // 9.6M
    const int elemBlocks = (elemTotal + 255) / 256;

    concat_kernel<<<elemBlocks, 256, 0, stream>>>(user_emb, item_emb, egoA);

    float* cur = egoA;
    float* nxt = egoB;
    for (int k = 0; k < 3; ++k) {
        hipMemsetAsync(nxt, 0, SZ, stream);
        spmm_atomic_kernel<<<N_EDGES / 4, 256, 0, stream>>>(rows, cols, vals, cur, nxt);
        int mode = (k == 0) ? 0 : ((k == 2) ? 2 : 1);
        noise_acc_kernel<<<elemBlocks, 256, 0, stream>>>(
            nxt, noise + (size_t)k * NN * EMB, acc, mode);
        float* tmp = cur; cur = nxt; nxt = tmp;
    }

    // prototype pass-through outputs
    hipMemcpyAsync(out + (size_t)NN * EMB, user_proto,
                   (size_t)PROTO * EMB * sizeof(float), hipMemcpyDeviceToDevice, stream);
    hipMemcpyAsync(out + (size_t)NN * EMB + (size_t)PROTO * EMB, item_proto,
                   (size_t)PROTO * EMB * sizeof(float), hipMemcpyDeviceToDevice, stream);
}

// Round 2
// 1927.508 us; speedup vs baseline: 2.8497x; 2.8497x over previous
//
#include <hip/hip_runtime.h>

#define USER_NUM 100000
#define ITEM_NUM 50000
#define NN (USER_NUM + ITEM_NUM)
#define EMB 64
#define N_EDGES 8000000
#define EPS_C 0.1f
#define PROTO 4000
#define SCAN_BLOCK 1024
#define NB_SCAN ((NN + SCAN_BLOCK - 1) / SCAN_BLOCK)   // 147

// ---------- common ----------
__global__ __launch_bounds__(256) void concat_kernel(const float* __restrict__ u,
                                                     const float* __restrict__ it,
                                                     float* __restrict__ out) {
    long i4 = (long)blockIdx.x * 256 + threadIdx.x;     // float4 index
    const long usz4 = (long)USER_NUM * EMB / 4;
    const long tot4 = (long)NN * EMB / 4;
    if (i4 >= tot4) return;
    const float4* src = (i4 < usz4) ? (const float4*)u : (const float4*)it;
    long j = (i4 < usz4) ? i4 : (i4 - usz4);
    ((float4*)out)[i4] = src[j];
}

// ---------- CSR build ----------
__global__ __launch_bounds__(256) void hist_kernel(const int* __restrict__ rows,
                                                   int* __restrict__ cnt) {
    int e = blockIdx.x * 256 + threadIdx.x;
    if (e >= N_EDGES) return;
    atomicAdd(&cnt[rows[e]], 1);
}

__global__ __launch_bounds__(SCAN_BLOCK) void scan1_kernel(const int* __restrict__ cnt,
                                                           int* __restrict__ row_start,
                                                           int* __restrict__ aux) {
    __shared__ int sh[SCAN_BLOCK];
    int tid = threadIdx.x;
    int i = blockIdx.x * SCAN_BLOCK + tid;
    int v = (i < NN) ? cnt[i] : 0;
    sh[tid] = v;
    __syncthreads();
    for (int off = 1; off < SCAN_BLOCK; off <<= 1) {
        int t = (tid >= off) ? sh[tid - off] : 0;
        __syncthreads();
        sh[tid] += t;
        __syncthreads();
    }
    if (i < NN) row_start[i] = sh[tid] - v;   // exclusive
    if (tid == SCAN_BLOCK - 1) aux[blockIdx.x] = sh[tid];
}

__global__ void scan2_kernel(int* __restrict__ aux) {
    if (threadIdx.x == 0 && blockIdx.x == 0) {
        int run = 0;
        for (int b = 0; b < NB_SCAN; ++b) {
            int t = aux[b];
            aux[b] = run;
            run += t;
        }
    }
}

__global__ __launch_bounds__(SCAN_BLOCK) void scan3_kernel(int* __restrict__ row_start,
                                                           const int* __restrict__ aux,
                                                           int* __restrict__ fill) {
    int i = blockIdx.x * SCAN_BLOCK + threadIdx.x;
    if (i >= NN) return;
    int rs = row_start[i] + aux[blockIdx.x];
    row_start[i] = rs;
    fill[i] = rs;
}

__global__ __launch_bounds__(256) void scatter_kernel(const int* __restrict__ rows,
                                                      const int* __restrict__ cols,
                                                      const float* __restrict__ vals,
                                                      int* __restrict__ fill,
                                                      int* __restrict__ ccols,
                                                      float* __restrict__ cvals) {
    int e = blockIdx.x * 256 + threadIdx.x;
    if (e >= N_EDGES) return;
    int r = rows[e];
    int pos = atomicAdd(&fill[r], 1);
    ccols[pos] = cols[e];
    cvals[pos] = vals[e];
}

// ---------- fused CSR SpMM + noise + accumulate ----------
// mode 0: acc = y'   mode 1: acc += y'   mode 2: acc = (acc + y') / 3
__global__ __launch_bounds__(256) void spmm_csr_fused(const int* __restrict__ row_start,
                                                      const int* __restrict__ cnt,
                                                      const int* __restrict__ ccols,
                                                      const float* __restrict__ cvals,
                                                      const float* __restrict__ x,
                                                      const float* __restrict__ noise_k,
                                                      float* __restrict__ ego_out,
                                                      float* __restrict__ acc,
                                                      int mode) {
    int row = (blockIdx.x * 256 + threadIdx.x) >> 6;   // one wave per row
    int lane = threadIdx.x & 63;
    if (row >= NN) return;
    int s = row_start[row];
    int end = s + cnt[row];

    float a0 = 0.f, a1 = 0.f, a2 = 0.f, a3 = 0.f;
    int e = s;
    for (; e + 4 <= end; e += 4) {
        int c0 = ccols[e], c1 = ccols[e + 1], c2 = ccols[e + 2], c3 = ccols[e + 3];
        float v0 = cvals[e], v1 = cvals[e + 1], v2 = cvals[e + 2], v3 = cvals[e + 3];
        a0 += v0 * x[(size_t)c0 * EMB + lane];
        a1 += v1 * x[(size_t)c1 * EMB + lane];
        a2 += v2 * x[(size_t)c2 * EMB + lane];
        a3 += v3 * x[(size_t)c3 * EMB + lane];
    }
    for (; e < end; ++e)
        a0 += cvals[e] * x[(size_t)ccols[e] * EMB + lane];
    float a = (a0 + a1) + (a2 + a3);

    size_t idx = (size_t)row * EMB + lane;
    float nv = noise_k[idx];
    float ssum = nv * nv;
    #pragma unroll
    for (int off = 32; off >= 1; off >>= 1) ssum += __shfl_xor(ssum, off, 64);
    float nrm = fmaxf(sqrtf(ssum), 1e-12f);
    float sgn = (a > 0.0f) ? 1.0f : ((a < 0.0f) ? -1.0f : 0.0f);
    float e1 = a + sgn * (nv / nrm) * EPS_C;

    ego_out[idx] = e1;
    if (mode == 0)      acc[idx] = e1;
    else if (mode == 1) acc[idx] += e1;
    else                acc[idx] = (acc[idx] + e1) * (1.0f / 3.0f);
}

// ---------- fallback (round-1 atomic path) ----------
__global__ __launch_bounds__(256) void spmm_atomic_kernel(const int* __restrict__ rows,
                                                          const int* __restrict__ cols,
                                                          const float* __restrict__ vals,
                                                          const float* __restrict__ x,
                                                          float* __restrict__ y) {
    long t = (long)blockIdx.x * 256 + threadIdx.x;
    int e = (int)(t >> 6);
    int lane = (int)(t & 63);
    if (e >= N_EDGES) return;
    int c = cols[e];
    int r = rows[e];
    float v = vals[e];
    atomicAdd(&y[(long)r * EMB + lane], v * x[(long)c * EMB + lane]);
}

__global__ __launch_bounds__(256) void noise_acc_kernel(float* __restrict__ ego,
                                                        const float* __restrict__ noise_k,
                                                        float* __restrict__ acc,
                                                        int mode) {
    long t = (long)blockIdx.x * 256 + threadIdx.x;
    int node = (int)(t >> 6);
    int lane = (int)(t & 63);
    if (node >= NN) return;
    long idx = (long)node * EMB + lane;
    float nv = noise_k[idx];
    float s = nv * nv;
    #pragma unroll
    for (int off = 32; off >= 1; off >>= 1) s += __shfl_xor(s, off, 64);
    float nrm = fmaxf(sqrtf(s), 1e-12f);
    float e0 = ego[idx];
    float sgn = (e0 > 0.0f) ? 1.0f : ((e0 < 0.0f) ? -1.0f : 0.0f);
    float e1 = e0 + sgn * (nv / nrm) * EPS_C;
    ego[idx] = e1;
    if (mode == 0)      acc[idx] = e1;
    else if (mode == 1) acc[idx] += e1;
    else                acc[idx] = (acc[idx] + e1) * (1.0f / 3.0f);
}

extern "C" void kernel_launch(void* const* d_in, const int* in_sizes, int n_in,
                              void* d_out, int out_size, void* d_ws, size_t ws_size,
                              hipStream_t stream) {
    const float* user_emb   = (const float*)d_in[0];
    const float* item_emb   = (const float*)d_in[1];
    const float* user_proto = (const float*)d_in[2];
    const float* item_proto = (const float*)d_in[3];
    const int*   rows       = (const int*)d_in[4];
    const int*   cols       = (const int*)d_in[5];
    const float* vals       = (const float*)d_in[6];
    const float* noise      = (const float*)d_in[7];
    float* out = (float*)d_out;

    const size_t EGO_SZ  = (size_t)NN * EMB * sizeof(float);        // 38.4 MB
    const size_t CNT_SZ  = ((size_t)NN * sizeof(int) + 255) & ~255; // padded
    const size_t AUX_SZ  = 1024;
    const size_t CSR_I   = (size_t)N_EDGES * sizeof(int);           // 32 MB
    const size_t CSR_F   = (size_t)N_EDGES * sizeof(float);         // 32 MB

    char* p = (char*)d_ws;
    float* egoA      = (float*)p;                 p += EGO_SZ;
    float* egoB      = (float*)p;                 p += EGO_SZ;
    int*   cnt       = (int*)p;                   p += CNT_SZ;
    int*   row_start = (int*)p;                   p += CNT_SZ;
    int*   fill      = (int*)p;                   p += CNT_SZ;
    int*   aux       = (int*)p;                   p += AUX_SZ;
    int*   ccols     = (int*)p;                   p += CSR_I;
    float* cvals     = (float*)p;                 p += CSR_F;
    const size_t required = (size_t)(p - (char*)d_ws);

    float* acc = out;
    const int elemTotal  = NN * EMB;
    const int elemBlocks = (elemTotal + 255) / 256;
    const int vecBlocks  = (elemTotal / 4 + 255) / 256;
    const int edgeBlocks = (N_EDGES + 255) / 256;
    const int rowWaveBlocks = (NN + 3) / 4;       // 4 waves (rows) per 256-thr block

    concat_kernel<<<vecBlocks, 256, 0, stream>>>(user_emb, item_emb, egoA);

    if (ws_size >= required) {
        // --- CSR build (once) ---
        hipMemsetAsync(cnt, 0, (size_t)NN * sizeof(int), stream);
        hist_kernel<<<edgeBlocks, 256, 0, stream>>>(rows, cnt);
        scan1_kernel<<<NB_SCAN, SCAN_BLOCK, 0, stream>>>(cnt, row_start, aux);
        scan2_kernel<<<1, 64, 0, stream>>>(aux);
        scan3_kernel<<<NB_SCAN, SCAN_BLOCK, 0, stream>>>(row_start, aux, fill);
        scatter_kernel<<<edgeBlocks, 256, 0, stream>>>(rows, cols, vals, fill, ccols, cvals);

        // --- 3 fused propagation layers ---
        float* cur = egoA;
        float* nxt = egoB;
        for (int k = 0; k < 3; ++k) {
            int mode = (k == 0) ? 0 : ((k == 2) ? 2 : 1);
            spmm_csr_fused<<<rowWaveBlocks, 256, 0, stream>>>(
                row_start, cnt, ccols, cvals, cur,
                noise + (size_t)k * NN * EMB, nxt, acc, mode);
            float* tmp = cur; cur = nxt; nxt = tmp;
        }
    } else {
        // --- fallback: atomic path ---
        float* cur = egoA;
        float* nxt = egoB;
        for (int k = 0; k < 3; ++k) {
            hipMemsetAsync(nxt, 0, EGO_SZ, stream);
            spmm_atomic_kernel<<<N_EDGES / 4, 256, 0, stream>>>(rows, cols, vals, cur, nxt);
            int mode = (k == 0) ? 0 : ((k == 2) ? 2 : 1);
            noise_acc_kernel<<<elemBlocks, 256, 0, stream>>>(
                nxt, noise + (size_t)k * NN * EMB, acc, mode);
            float* tmp = cur; cur = nxt; nxt = tmp;
        }
    }

    hipMemcpyAsync(out + (size_t)NN * EMB, user_proto,
                   (size_t)PROTO * EMB * sizeof(float), hipMemcpyDeviceToDevice, stream);
    hipMemcpyAsync(out + (size_t)NN * EMB + (size_t)PROTO * EMB, item_proto,
                   (size_t)PROTO * EMB * sizeof(float), hipMemcpyDeviceToDevice, stream);
}